// Round 1
// baseline (441.216 us; speedup 1.0000x reference)
//
#include <hip/hip_runtime.h>
#include <hip/hip_bf16.h>

#define N_NODE  50000
#define N_PAD   50048   // 391 * 128
#define N_GRAPH 1024
#define DD      512

typedef __attribute__((ext_vector_type(8))) short bf16x8;
typedef __attribute__((ext_vector_type(4))) float f32x4;

__device__ __forceinline__ unsigned short f2bf(float f) {
  unsigned int u = __builtin_bit_cast(unsigned int, f);
  return (unsigned short)((u + 0x7FFFu + ((u >> 16) & 1u)) >> 16);  // RTN-even
}

__device__ __forceinline__ void gload16(const void* g, void* l) {
  __builtin_amdgcn_global_load_lds(
      (const __attribute__((address_space(1))) unsigned int*)g,
      (__attribute__((address_space(3))) unsigned int*)l, 16, 0, 0);
}

// ---- cast kernels -----------------------------------------------------------

__global__ void cast_pad_kernel(const float* __restrict__ src,
                                unsigned short* __restrict__ dst,
                                int srcRows, int dstRows) {
  long long base = ((long long)blockIdx.x * blockDim.x + threadIdx.x) * 8;
  if (base >= (long long)dstRows * DD) return;
  int row = (int)(base >> 9);
  bf16x8 o;
  if (row < srcRows) {
    float4 x0 = reinterpret_cast<const float4*>(src + base)[0];
    float4 x1 = reinterpret_cast<const float4*>(src + base)[1];
    o[0] = (short)f2bf(x0.x); o[1] = (short)f2bf(x0.y);
    o[2] = (short)f2bf(x0.z); o[3] = (short)f2bf(x0.w);
    o[4] = (short)f2bf(x1.x); o[5] = (short)f2bf(x1.y);
    o[6] = (short)f2bf(x1.z); o[7] = (short)f2bf(x1.w);
  } else {
    for (int i = 0; i < 8; ++i) o[i] = 0;
  }
  *reinterpret_cast<bf16x8*>(dst + base) = o;
}

struct WPtrs { const float* p[8]; };

__global__ void cast_w_kernel(WPtrs ps, unsigned short* __restrict__ dst) {
  long long base = ((long long)blockIdx.x * blockDim.x + threadIdx.x) * 8;
  int mat = (int)(base >> 18);           // 512*512 = 2^18
  int off = (int)(base & 262143LL);
  const float* s = ps.p[mat] + off;
  float4 x0 = reinterpret_cast<const float4*>(s)[0];
  float4 x1 = reinterpret_cast<const float4*>(s)[1];
  bf16x8 o;
  o[0] = (short)f2bf(x0.x); o[1] = (short)f2bf(x0.y);
  o[2] = (short)f2bf(x0.z); o[3] = (short)f2bf(x0.w);
  o[4] = (short)f2bf(x1.x); o[5] = (short)f2bf(x1.y);
  o[6] = (short)f2bf(x1.z); o[7] = (short)f2bf(x1.w);
  *reinterpret_cast<bf16x8*>(dst + base) = o;
}

// ---- GEMM core: C_tile(128x128) += A[M,512] @ B[N,512]^T, bf16 MFMA --------

__device__ __forceinline__ void gemm_core(
    const unsigned short* __restrict__ A, const unsigned short* __restrict__ B,
    unsigned short* As, unsigned short* Bs,
    int brow, int bcol, int wr, int wc, int lane, int wid, f32x4 acc[4][4]) {
  const int rA = wr * 64 + (lane & 15);
  const int rB = wc * 64 + (lane & 15);
  const int kq = (lane >> 4) * 8;
  const int srow = lane >> 2;        // 0..15
  const int scol = (lane & 3) * 8;   // 0,8,16,24
  for (int kt = 0; kt < DD; kt += 32) {
    __syncthreads();
    #pragma unroll
    for (int i = 0; i < 2; ++i) {
      int chunk = wid * 2 + i;
      int r = chunk * 16 + srow;
      gload16(A + (long long)(brow + r) * DD + kt + scol, As + chunk * 512);
      gload16(B + (long long)(bcol + r) * DD + kt + scol, Bs + chunk * 512);
    }
    __syncthreads();
    bf16x8 a[4], b[4];
    #pragma unroll
    for (int m = 0; m < 4; ++m)
      a[m] = *reinterpret_cast<const bf16x8*>(As + (rA + m * 16) * 32 + kq);
    #pragma unroll
    for (int n = 0; n < 4; ++n)
      b[n] = *reinterpret_cast<const bf16x8*>(Bs + (rB + n * 16) * 32 + kq);
    #pragma unroll
    for (int m = 0; m < 4; ++m)
      #pragma unroll
      for (int n = 0; n < 4; ++n)
        acc[m][n] = __builtin_amdgcn_mfma_f32_16x16x32_bf16(a[m], b[n], acc[m][n], 0, 0, 0);
  }
}

// ---- FF GEMM: C = relu(A@W^T + bias)  [DUAL: + A2@W2^T + bias2] ------------

template <int DUAL>
__global__ __launch_bounds__(256, 2) void gemm_ff_kernel(
    const unsigned short* __restrict__ A, const unsigned short* __restrict__ W,
    const float* __restrict__ bias, unsigned short* __restrict__ C,
    const unsigned short* __restrict__ A2, const unsigned short* __restrict__ W2,
    const float* __restrict__ bias2) {
  __shared__ unsigned short As[128 * 32];
  __shared__ unsigned short Bs[128 * 32];
  const int lane = threadIdx.x & 63, wid = threadIdx.x >> 6;
  const int wr = wid >> 1, wc = wid & 1;
  const int brow = blockIdx.y * 128, bcol = blockIdx.x * 128;

  f32x4 zero = {0.f, 0.f, 0.f, 0.f};
  f32x4 acc[4][4];
  #pragma unroll
  for (int m = 0; m < 4; ++m)
    #pragma unroll
    for (int n = 0; n < 4; ++n) acc[m][n] = zero;

  gemm_core(A, W, As, Bs, brow, bcol, wr, wc, lane, wid, acc);

  float bv[4];
  #pragma unroll
  for (int n = 0; n < 4; ++n) bv[n] = bias[bcol + wc * 64 + n * 16 + (lane & 15)];

  if constexpr (DUAL) {
    float r[4][4][4];
    #pragma unroll
    for (int m = 0; m < 4; ++m)
      #pragma unroll
      for (int n = 0; n < 4; ++n)
        #pragma unroll
        for (int j = 0; j < 4; ++j)
          r[m][n][j] = fmaxf(acc[m][n][j] + bv[n], 0.f);
    #pragma unroll
    for (int m = 0; m < 4; ++m)
      #pragma unroll
      for (int n = 0; n < 4; ++n) acc[m][n] = zero;

    gemm_core(A2, W2, As, Bs, brow, bcol, wr, wc, lane, wid, acc);

    float b2[4];
    #pragma unroll
    for (int n = 0; n < 4; ++n) b2[n] = bias2[bcol + wc * 64 + n * 16 + (lane & 15)];

    #pragma unroll
    for (int m = 0; m < 4; ++m) {
      const int row = brow + wr * 64 + m * 16 + (lane >> 4) * 4;
      #pragma unroll
      for (int j = 0; j < 4; ++j)
        #pragma unroll
        for (int n = 0; n < 4; ++n) {
          const int col = bcol + wc * 64 + n * 16 + (lane & 15);
          float v = r[m][n][j] + acc[m][n][j] + b2[n];
          C[(long long)(row + j) * DD + col] = f2bf(v);
        }
    }
  } else {
    #pragma unroll
    for (int m = 0; m < 4; ++m) {
      const int row = brow + wr * 64 + m * 16 + (lane >> 4) * 4;
      #pragma unroll
      for (int j = 0; j < 4; ++j)
        #pragma unroll
        for (int n = 0; n < 4; ++n) {
          const int col = bcol + wc * 64 + n * 16 + (lane & 15);
          float v = fmaxf(acc[m][n][j] + bv[n], 0.f);
          C[(long long)(row + j) * DD + col] = f2bf(v);
        }
    }
  }
}

// ---- res GEMM + fused JSD reduction ----------------------------------------

__global__ __launch_bounds__(256, 2) void gemm_jsd_kernel(
    const unsigned short* __restrict__ A, const unsigned short* __restrict__ B,
    const int* __restrict__ batch, double* __restrict__ accum) {
  __shared__ unsigned short As[128 * 32];
  __shared__ unsigned short Bs[128 * 32];
  __shared__ int sbatch[128];
  __shared__ float sred[16];
  const int lane = threadIdx.x & 63, wid = threadIdx.x >> 6;
  const int wr = wid >> 1, wc = wid & 1;
  const int brow = blockIdx.y * 128, bcol = blockIdx.x * 128;

  if (threadIdx.x < 128) {
    int gr = brow + threadIdx.x;
    sbatch[threadIdx.x] = (gr < N_NODE) ? batch[gr] : -1;
  }

  f32x4 zero = {0.f, 0.f, 0.f, 0.f};
  f32x4 acc[4][4];
  #pragma unroll
  for (int m = 0; m < 4; ++m)
    #pragma unroll
    for (int n = 0; n < 4; ++n) acc[m][n] = zero;

  gemm_core(A, B, As, Bs, brow, bcol, wr, wc, lane, wid, acc);

  const float LN2 = 0.69314718055994530942f;
  float pos = 0.f, neg = 0.f;
  #pragma unroll
  for (int m = 0; m < 4; ++m) {
    #pragma unroll
    for (int j = 0; j < 4; ++j) {
      const int lr = wr * 64 + m * 16 + (lane >> 4) * 4 + j;
      const bool valid = (brow + lr) < N_NODE;
      const int bg = sbatch[lr];
      #pragma unroll
      for (int n = 0; n < 4; ++n) {
        const int col = bcol + wc * 64 + n * 16 + (lane & 15);
        float v = acc[m][n][j];
        float av = fabsf(v);
        float l1p = log1pf(__expf(-av));
        float spn = fmaxf(-v, 0.f) + l1p;   // softplus(-v), stable
        if (valid) {
          if (col == bg) pos += LN2 - spn;            // log2 - softplus(-p)
          else           neg += spn + v - LN2;        // softplus(-q)+q-log2
        }
      }
    }
  }
  #pragma unroll
  for (int off = 32; off > 0; off >>= 1) {
    pos += __shfl_down(pos, off);
    neg += __shfl_down(neg, off);
  }
  if (lane == 0) { sred[wid] = pos; sred[8 + wid] = neg; }
  __syncthreads();
  if (threadIdx.x == 0) {
    float p = sred[0] + sred[1] + sred[2] + sred[3];
    float q = sred[8] + sred[9] + sred[10] + sred[11];
    atomicAdd(accum, (double)p);
    atomicAdd(accum + 1, (double)q);
  }
}

__global__ void finalize_kernel(const double* __restrict__ accum,
                                float* __restrict__ out) {
  if (threadIdx.x == 0 && blockIdx.x == 0) {
    double Epos = accum[0] / (double)N_NODE;
    double Eneg = accum[1] / ((double)N_NODE * (double)(N_GRAPH - 1));
    out[0] = (float)(Eneg - Epos);
  }
}

// ---- launch -----------------------------------------------------------------

extern "C" void kernel_launch(void* const* d_in, const int* in_sizes, int n_in,
                              void* d_out, int out_size, void* d_ws, size_t ws_size,
                              hipStream_t stream) {
  const float* node  = (const float*)d_in[0];
  const float* graph = (const float*)d_in[1];
  const int*   batch = (const int*)d_in[2];
  const float* lw0 = (const float*)d_in[3];
  const float* lb0 = (const float*)d_in[4];
  const float* lw1 = (const float*)d_in[5];
  const float* lb1 = (const float*)d_in[6];
  const float* lw2 = (const float*)d_in[7];
  const float* lb2 = (const float*)d_in[8];
  const float* lws = (const float*)d_in[9];
  const float* lbs = (const float*)d_in[10];
  const float* gw0 = (const float*)d_in[11];
  const float* gb0 = (const float*)d_in[12];
  const float* gw1 = (const float*)d_in[13];
  const float* gb1 = (const float*)d_in[14];
  const float* gw2 = (const float*)d_in[15];
  const float* gb2 = (const float*)d_in[16];
  const float* gws = (const float*)d_in[17];
  const float* gbs = (const float*)d_in[18];

  // workspace layout (bytes, 256-aligned)
  char* ws = (char*)d_ws;
  double*         accum = (double*)ws;                          // 16 B
  unsigned short* WB  = (unsigned short*)(ws + 256);            // 8 x 512x512 bf16
  unsigned short* XB  = (unsigned short*)(ws + 4194560LL);      // [N_PAD,512] bf16
  unsigned short* H1  = (unsigned short*)(ws + 55443712LL);
  unsigned short* H2  = (unsigned short*)(ws + 106692864LL);
  unsigned short* GXB = (unsigned short*)(ws + 157942016LL);
  unsigned short* GH1 = (unsigned short*)(ws + 158990592LL);
  unsigned short* GH2 = (unsigned short*)(ws + 160039168LL);
  if (ws_size < 161087744ULL) return;  // workspace too small: fail loudly

  hipMemsetAsync(accum, 0, 16, stream);

  WPtrs wp;
  wp.p[0] = lw0; wp.p[1] = lw1; wp.p[2] = lw2; wp.p[3] = lws;
  wp.p[4] = gw0; wp.p[5] = gw1; wp.p[6] = gw2; wp.p[7] = gws;
  cast_w_kernel<<<1024, 256, 0, stream>>>(wp, WB);
  cast_pad_kernel<<<12512, 256, 0, stream>>>(node, XB, N_NODE, N_PAD);
  cast_pad_kernel<<<256, 256, 0, stream>>>(graph, GXB, N_GRAPH, N_GRAPH);

  dim3 blk(256);
  dim3 gl(4, 391);   // l-FF GEMMs: N=512, M=50048
  dim3 gg(4, 8);     // g-FF GEMMs: N=512, M=1024
  dim3 gr(8, 391);   // res: N=1024, M=50048

  gemm_ff_kernel<0><<<gl, blk, 0, stream>>>(XB, WB + 0 * 262144, lb0, H1, nullptr, nullptr, nullptr);
  gemm_ff_kernel<0><<<gl, blk, 0, stream>>>(H1, WB + 1 * 262144, lb1, H2, nullptr, nullptr, nullptr);
  gemm_ff_kernel<1><<<gl, blk, 0, stream>>>(H2, WB + 2 * 262144, lb2, H1, XB, WB + 3 * 262144, lbs);

  gemm_ff_kernel<0><<<gg, blk, 0, stream>>>(GXB, WB + 4 * 262144, gb0, GH1, nullptr, nullptr, nullptr);
  gemm_ff_kernel<0><<<gg, blk, 0, stream>>>(GH1, WB + 5 * 262144, gb1, GH2, nullptr, nullptr, nullptr);
  gemm_ff_kernel<1><<<gg, blk, 0, stream>>>(GH2, WB + 6 * 262144, gb2, GH1, GXB, WB + 7 * 262144, gbs);

  gemm_jsd_kernel<<<gr, blk, 0, stream>>>(H1, GH1, batch, accum);
  finalize_kernel<<<1, 64, 0, stream>>>(accum, (float*)d_out);
}

// Round 2
// 420.489 us; speedup vs baseline: 1.0493x; 1.0493x over previous
//
#include <hip/hip_runtime.h>
#include <hip/hip_bf16.h>

#define N_NODE  50000
#define N_PAD   50048   // 391 * 128
#define N_GRAPH 1024
#define DD      512

typedef __attribute__((ext_vector_type(8))) short bf16x8;
typedef __attribute__((ext_vector_type(4))) float f32x4;

__device__ __forceinline__ unsigned short f2bf(float f) {
  unsigned int u = __builtin_bit_cast(unsigned int, f);
  return (unsigned short)((u + 0x7FFFu + ((u >> 16) & 1u)) >> 16);  // RTN-even
}

__device__ __forceinline__ void gload16(const void* g, void* l) {
  __builtin_amdgcn_global_load_lds(
      (const __attribute__((address_space(1))) unsigned int*)g,
      (__attribute__((address_space(3))) unsigned int*)l, 16, 0, 0);
}

// ---- cast kernels -----------------------------------------------------------

__global__ void cast_pad_kernel(const float* __restrict__ src,
                                unsigned short* __restrict__ dst,
                                int srcRows, int dstRows) {
  long long base = ((long long)blockIdx.x * blockDim.x + threadIdx.x) * 8;
  if (base >= (long long)dstRows * DD) return;
  int row = (int)(base >> 9);
  bf16x8 o;
  if (row < srcRows) {
    float4 x0 = reinterpret_cast<const float4*>(src + base)[0];
    float4 x1 = reinterpret_cast<const float4*>(src + base)[1];
    o[0] = (short)f2bf(x0.x); o[1] = (short)f2bf(x0.y);
    o[2] = (short)f2bf(x0.z); o[3] = (short)f2bf(x0.w);
    o[4] = (short)f2bf(x1.x); o[5] = (short)f2bf(x1.y);
    o[6] = (short)f2bf(x1.z); o[7] = (short)f2bf(x1.w);
  } else {
    for (int i = 0; i < 8; ++i) o[i] = 0;
  }
  *reinterpret_cast<bf16x8*>(dst + base) = o;
}

struct WPtrs { const float* p[8]; };

__global__ void cast_w_kernel(WPtrs ps, unsigned short* __restrict__ dst) {
  long long base = ((long long)blockIdx.x * blockDim.x + threadIdx.x) * 8;
  int mat = (int)(base >> 18);           // 512*512 = 2^18
  int off = (int)(base & 262143LL);
  const float* s = ps.p[mat] + off;
  float4 x0 = reinterpret_cast<const float4*>(s)[0];
  float4 x1 = reinterpret_cast<const float4*>(s)[1];
  bf16x8 o;
  o[0] = (short)f2bf(x0.x); o[1] = (short)f2bf(x0.y);
  o[2] = (short)f2bf(x0.z); o[3] = (short)f2bf(x0.w);
  o[4] = (short)f2bf(x1.x); o[5] = (short)f2bf(x1.y);
  o[6] = (short)f2bf(x1.z); o[7] = (short)f2bf(x1.w);
  *reinterpret_cast<bf16x8*>(dst + base) = o;
}

// ---- GEMM core: C_tile(128x128) += A[M,512] @ B[N,512]^T, bf16 MFMA --------

__device__ __forceinline__ void gemm_core(
    const unsigned short* __restrict__ A, const unsigned short* __restrict__ B,
    unsigned short* As, unsigned short* Bs,
    int brow, int bcol, int wr, int wc, int lane, int wid, f32x4 acc[4][4]) {
  const int rA = wr * 64 + (lane & 15);
  const int rB = wc * 64 + (lane & 15);
  const int kq = (lane >> 4) * 8;
  const int srow = lane >> 2;        // 0..15
  const int scol = (lane & 3) * 8;   // 0,8,16,24
  for (int kt = 0; kt < DD; kt += 32) {
    __syncthreads();
    #pragma unroll
    for (int i = 0; i < 2; ++i) {
      int chunk = wid * 2 + i;
      int r = chunk * 16 + srow;
      gload16(A + (long long)(brow + r) * DD + kt + scol, As + chunk * 512);
      gload16(B + (long long)(bcol + r) * DD + kt + scol, Bs + chunk * 512);
    }
    __syncthreads();
    bf16x8 a[4], b[4];
    #pragma unroll
    for (int m = 0; m < 4; ++m)
      a[m] = *reinterpret_cast<const bf16x8*>(As + (rA + m * 16) * 32 + kq);
    #pragma unroll
    for (int n = 0; n < 4; ++n)
      b[n] = *reinterpret_cast<const bf16x8*>(Bs + (rB + n * 16) * 32 + kq);
    #pragma unroll
    for (int m = 0; m < 4; ++m)
      #pragma unroll
      for (int n = 0; n < 4; ++n)
        acc[m][n] = __builtin_amdgcn_mfma_f32_16x16x32_bf16(a[m], b[n], acc[m][n], 0, 0, 0);
  }
}

// ---- FF GEMM: C = relu(A@W^T + bias)  [DUAL: + A2@W2^T + bias2] ------------

template <int DUAL>
__global__ __launch_bounds__(256, 2) void gemm_ff_kernel(
    const unsigned short* __restrict__ A, const unsigned short* __restrict__ W,
    const float* __restrict__ bias, unsigned short* __restrict__ C,
    const unsigned short* __restrict__ A2, const unsigned short* __restrict__ W2,
    const float* __restrict__ bias2) {
  __shared__ unsigned short As[128 * 32];
  __shared__ unsigned short Bs[128 * 32];
  const int lane = threadIdx.x & 63, wid = threadIdx.x >> 6;
  const int wr = wid >> 1, wc = wid & 1;
  const int brow = blockIdx.y * 128, bcol = blockIdx.x * 128;

  f32x4 zero = {0.f, 0.f, 0.f, 0.f};
  f32x4 acc[4][4];
  #pragma unroll
  for (int m = 0; m < 4; ++m)
    #pragma unroll
    for (int n = 0; n < 4; ++n) acc[m][n] = zero;

  gemm_core(A, W, As, Bs, brow, bcol, wr, wc, lane, wid, acc);

  float bv[4];
  #pragma unroll
  for (int n = 0; n < 4; ++n) bv[n] = bias[bcol + wc * 64 + n * 16 + (lane & 15)];

  if constexpr (DUAL) {
    float r[4][4][4];
    #pragma unroll
    for (int m = 0; m < 4; ++m)
      #pragma unroll
      for (int n = 0; n < 4; ++n)
        #pragma unroll
        for (int j = 0; j < 4; ++j)
          r[m][n][j] = fmaxf(acc[m][n][j] + bv[n], 0.f);
    #pragma unroll
    for (int m = 0; m < 4; ++m)
      #pragma unroll
      for (int n = 0; n < 4; ++n) acc[m][n] = zero;

    gemm_core(A2, W2, As, Bs, brow, bcol, wr, wc, lane, wid, acc);

    float b2[4];
    #pragma unroll
    for (int n = 0; n < 4; ++n) b2[n] = bias2[bcol + wc * 64 + n * 16 + (lane & 15)];

    #pragma unroll
    for (int m = 0; m < 4; ++m) {
      const int row = brow + wr * 64 + m * 16 + (lane >> 4) * 4;
      #pragma unroll
      for (int j = 0; j < 4; ++j)
        #pragma unroll
        for (int n = 0; n < 4; ++n) {
          const int col = bcol + wc * 64 + n * 16 + (lane & 15);
          float v = r[m][n][j] + acc[m][n][j] + b2[n];
          C[(long long)(row + j) * DD + col] = f2bf(v);
        }
    }
  } else {
    #pragma unroll
    for (int m = 0; m < 4; ++m) {
      const int row = brow + wr * 64 + m * 16 + (lane >> 4) * 4;
      #pragma unroll
      for (int j = 0; j < 4; ++j)
        #pragma unroll
        for (int n = 0; n < 4; ++n) {
          const int col = bcol + wc * 64 + n * 16 + (lane & 15);
          float v = fmaxf(acc[m][n][j] + bv[n], 0.f);
          C[(long long)(row + j) * DD + col] = f2bf(v);
        }
    }
  }
}

// ---- res GEMM + fused JSD reduction ----------------------------------------
//
// Per element: spn = softplus(-v) via hardware exp2/log2 intrinsics.
//   neg contribution (all elements, incl diag & zero-pad rows) = spn + v - LN2
//   zero-padded rows give v=0 -> spn+v = ln2 -> cancels against the analytic
//   per-element LN2 subtracted in finalize. Diagonal terms corrected there too.
// accum[0] = sum_diag (LN2 - spn)        (E_pos raw sum)
// accum[1] = sum_all  (spn + v)
// accum[2] = sum_diag (spn + v)

__global__ __launch_bounds__(256, 2) void gemm_jsd_kernel(
    const unsigned short* __restrict__ A, const unsigned short* __restrict__ B,
    const int* __restrict__ batch, double* __restrict__ accum) {
  __shared__ unsigned short As[128 * 32];
  __shared__ unsigned short Bs[128 * 32];
  __shared__ int sbatch[128];
  __shared__ float sred[12];
  const int lane = threadIdx.x & 63, wid = threadIdx.x >> 6;
  const int wr = wid >> 1, wc = wid & 1;
  const int brow = blockIdx.y * 128, bcol = blockIdx.x * 128;

  if (threadIdx.x < 128) {
    int gr = brow + threadIdx.x;
    sbatch[threadIdx.x] = (gr < N_NODE) ? batch[gr] : -1;  // -1: never matches a col
  }

  f32x4 zero = {0.f, 0.f, 0.f, 0.f};
  f32x4 acc[4][4];
  #pragma unroll
  for (int m = 0; m < 4; ++m)
    #pragma unroll
    for (int n = 0; n < 4; ++n) acc[m][n] = zero;

  gemm_core(A, B, As, Bs, brow, bcol, wr, wc, lane, wid, acc);

  const float LN2 = 0.69314718055994530942f;
  float sAll = 0.f, sPos = 0.f, sDiag = 0.f;
  #pragma unroll
  for (int m = 0; m < 4; ++m) {
    #pragma unroll
    for (int j = 0; j < 4; ++j) {
      const int lr = wr * 64 + m * 16 + (lane >> 4) * 4 + j;
      const int bg = sbatch[lr];
      #pragma unroll
      for (int n = 0; n < 4; ++n) {
        const int col = bcol + wc * 64 + n * 16 + (lane & 15);
        float v = acc[m][n][j];
        // softplus(-v) = max(-v,0) + ln(1 + e^{-|v|})   (hw exp/log, ~1e-7 abs err)
        float t = __expf(-fabsf(v));
        float spn = fmaxf(-v, 0.f) + __logf(1.0f + t);
        sAll += spn + v;
        if (col == bg) {               // rare: exec-masked skip almost always
          sPos += LN2 - spn;
          sDiag += spn + v;
        }
      }
    }
  }
  #pragma unroll
  for (int off = 32; off > 0; off >>= 1) {
    sAll  += __shfl_down(sAll, off);
    sPos  += __shfl_down(sPos, off);
    sDiag += __shfl_down(sDiag, off);
  }
  if (lane == 0) { sred[wid] = sPos; sred[4 + wid] = sAll; sred[8 + wid] = sDiag; }
  __syncthreads();
  if (threadIdx.x == 0) {
    float p = sred[0] + sred[1] + sred[2] + sred[3];
    float a = sred[4] + sred[5] + sred[6] + sred[7];
    float d = sred[8] + sred[9] + sred[10] + sred[11];
    atomicAdd(accum,     (double)p);
    atomicAdd(accum + 1, (double)a);
    atomicAdd(accum + 2, (double)d);
  }
}

__global__ void finalize_kernel(const double* __restrict__ accum,
                                float* __restrict__ out) {
  if (threadIdx.x == 0 && blockIdx.x == 0) {
    const double LN2 = 0.6931471805599453094172321;
    double posSum = accum[0];
    // sum over non-diag of (spn+v-LN2):
    //   = (sum_all(spn+v) - sum_diag(spn+v)) - (N_PAD*G - N_NODE)*LN2
    // (zero-pad rows contribute spn+v = ln2 each, cancelled by the LN2 term)
    double negSum = (accum[1] - accum[2])
                  - ((double)N_PAD * N_GRAPH - (double)N_NODE) * LN2;
    double Epos = posSum / (double)N_NODE;
    double Eneg = negSum / ((double)N_NODE * (double)(N_GRAPH - 1));
    out[0] = (float)(Eneg - Epos);
  }
}

// ---- launch -----------------------------------------------------------------

extern "C" void kernel_launch(void* const* d_in, const int* in_sizes, int n_in,
                              void* d_out, int out_size, void* d_ws, size_t ws_size,
                              hipStream_t stream) {
  const float* node  = (const float*)d_in[0];
  const float* graph = (const float*)d_in[1];
  const int*   batch = (const int*)d_in[2];
  const float* lw0 = (const float*)d_in[3];
  const float* lb0 = (const float*)d_in[4];
  const float* lw1 = (const float*)d_in[5];
  const float* lb1 = (const float*)d_in[6];
  const float* lw2 = (const float*)d_in[7];
  const float* lb2 = (const float*)d_in[8];
  const float* lws = (const float*)d_in[9];
  const float* lbs = (const float*)d_in[10];
  const float* gw0 = (const float*)d_in[11];
  const float* gb0 = (const float*)d_in[12];
  const float* gw1 = (const float*)d_in[13];
  const float* gb1 = (const float*)d_in[14];
  const float* gw2 = (const float*)d_in[15];
  const float* gb2 = (const float*)d_in[16];
  const float* gws = (const float*)d_in[17];
  const float* gbs = (const float*)d_in[18];

  // workspace layout (bytes, 256-aligned)
  char* ws = (char*)d_ws;
  double*         accum = (double*)ws;                          // 24 B
  unsigned short* WB  = (unsigned short*)(ws + 256);            // 8 x 512x512 bf16
  unsigned short* XB  = (unsigned short*)(ws + 4194560LL);      // [N_PAD,512] bf16
  unsigned short* H1  = (unsigned short*)(ws + 55443712LL);
  unsigned short* H2  = (unsigned short*)(ws + 106692864LL);
  unsigned short* GXB = (unsigned short*)(ws + 157942016LL);
  unsigned short* GH1 = (unsigned short*)(ws + 158990592LL);
  unsigned short* GH2 = (unsigned short*)(ws + 160039168LL);
  if (ws_size < 161087744ULL) return;  // workspace too small: fail loudly

  hipMemsetAsync(accum, 0, 32, stream);

  WPtrs wp;
  wp.p[0] = lw0; wp.p[1] = lw1; wp.p[2] = lw2; wp.p[3] = lws;
  wp.p[4] = gw0; wp.p[5] = gw1; wp.p[6] = gw2; wp.p[7] = gws;
  cast_w_kernel<<<1024, 256, 0, stream>>>(wp, WB);
  cast_pad_kernel<<<12512, 256, 0, stream>>>(node, XB, N_NODE, N_PAD);
  cast_pad_kernel<<<256, 256, 0, stream>>>(graph, GXB, N_GRAPH, N_GRAPH);

  dim3 blk(256);
  dim3 gl(4, 391);   // l-FF GEMMs: N=512, M=50048
  dim3 gg(4, 8);     // g-FF GEMMs: N=512, M=1024
  dim3 gr(8, 391);   // res: N=1024, M=50048

  gemm_ff_kernel<0><<<gl, blk, 0, stream>>>(XB, WB + 0 * 262144, lb0, H1, nullptr, nullptr, nullptr);
  gemm_ff_kernel<0><<<gl, blk, 0, stream>>>(H1, WB + 1 * 262144, lb1, H2, nullptr, nullptr, nullptr);
  gemm_ff_kernel<1><<<gl, blk, 0, stream>>>(H2, WB + 2 * 262144, lb2, H1, XB, WB + 3 * 262144, lbs);

  gemm_ff_kernel<0><<<gg, blk, 0, stream>>>(GXB, WB + 4 * 262144, gb0, GH1, nullptr, nullptr, nullptr);
  gemm_ff_kernel<0><<<gg, blk, 0, stream>>>(GH1, WB + 5 * 262144, gb1, GH2, nullptr, nullptr, nullptr);
  gemm_ff_kernel<1><<<gg, blk, 0, stream>>>(GH2, WB + 6 * 262144, gb2, GH1, GXB, WB + 7 * 262144, gbs);

  gemm_jsd_kernel<<<gr, blk, 0, stream>>>(H1, GH1, batch, accum);
  finalize_kernel<<<1, 64, 0, stream>>>(accum, (float*)d_out);
}

// Round 3
// 339.930 us; speedup vs baseline: 1.2980x; 1.2370x over previous
//
#include <hip/hip_runtime.h>
#include <hip/hip_bf16.h>

#define N_NODE  50000
#define N_PAD   50048   // 391 * 128
#define N_GRAPH 1024
#define DD      512
#define BK      64
#define NT      (DD / BK)   // 8 K-steps

typedef __attribute__((ext_vector_type(8))) short bf16x8;
typedef __attribute__((ext_vector_type(4))) float f32x4;

__device__ __forceinline__ unsigned short f2bf(float f) {
  unsigned int u = __builtin_bit_cast(unsigned int, f);
  return (unsigned short)((u + 0x7FFFu + ((u >> 16) & 1u)) >> 16);  // RTN-even
}

__device__ __forceinline__ void gload16(const void* g, void* l) {
  __builtin_amdgcn_global_load_lds(
      (const __attribute__((address_space(1))) unsigned int*)g,
      (__attribute__((address_space(3))) unsigned int*)l, 16, 0, 0);
}

// T1: bijective XCD-chunk remap (m204 variant; works for any nwg)
__device__ __forceinline__ int xcd_remap(int bid, int nwg) {
  int xcd = bid & 7;
  int local = bid >> 3;
  int q = nwg >> 3, r = nwg & 7;
  int base = (xcd < r) ? xcd * (q + 1) : r * (q + 1) + (xcd - r) * q;
  return base + local;
}

// ---- cast kernels -----------------------------------------------------------

__global__ void cast_pad_kernel(const float* __restrict__ src,
                                unsigned short* __restrict__ dst,
                                int srcRows, int dstRows) {
  long long base = ((long long)blockIdx.x * blockDim.x + threadIdx.x) * 8;
  if (base >= (long long)dstRows * DD) return;
  int row = (int)(base >> 9);
  bf16x8 o;
  if (row < srcRows) {
    float4 x0 = reinterpret_cast<const float4*>(src + base)[0];
    float4 x1 = reinterpret_cast<const float4*>(src + base)[1];
    o[0] = (short)f2bf(x0.x); o[1] = (short)f2bf(x0.y);
    o[2] = (short)f2bf(x0.z); o[3] = (short)f2bf(x0.w);
    o[4] = (short)f2bf(x1.x); o[5] = (short)f2bf(x1.y);
    o[6] = (short)f2bf(x1.z); o[7] = (short)f2bf(x1.w);
  } else {
    for (int i = 0; i < 8; ++i) o[i] = 0;
  }
  *reinterpret_cast<bf16x8*>(dst + base) = o;
}

struct WPtrs { const float* p[8]; };

__global__ void cast_w_kernel(WPtrs ps, unsigned short* __restrict__ dst) {
  long long base = ((long long)blockIdx.x * blockDim.x + threadIdx.x) * 8;
  int mat = (int)(base >> 18);           // 512*512 = 2^18
  int off = (int)(base & 262143LL);
  const float* s = ps.p[mat] + off;
  float4 x0 = reinterpret_cast<const float4*>(s)[0];
  float4 x1 = reinterpret_cast<const float4*>(s)[1];
  bf16x8 o;
  o[0] = (short)f2bf(x0.x); o[1] = (short)f2bf(x0.y);
  o[2] = (short)f2bf(x0.z); o[3] = (short)f2bf(x0.w);
  o[4] = (short)f2bf(x1.x); o[5] = (short)f2bf(x1.y);
  o[6] = (short)f2bf(x1.z); o[7] = (short)f2bf(x1.w);
  *reinterpret_cast<bf16x8*>(dst + base) = o;
}

// ---- staging: one 128x64 bf16 tile -> LDS, XOR-swizzled content -------------
// LDS layout: linear [128][64] elements; LDS[r][slot s] holds G[r][s ^ (r&7)]
// (slots are 8-element/16-byte units). global_load_lds writes linearly at
// wave-uniform base + lane*16, so the swizzle is applied on the GLOBAL source
// address (rule 21: both-sides-or-neither).

__device__ __forceinline__ void stage_tile(const unsigned short* __restrict__ G,
                                           long long rowBase, int kcol,
                                           unsigned short* lds, int tid) {
  const int rr   = tid >> 3;                     // row within 32-row round
  const int csrc = (tid & 7) ^ (rr & 7);         // inverse-swizzled source slot
  const unsigned short* src = G + (rowBase + rr) * DD + kcol + csrc * 8;
  unsigned short* dstbase = lds + ((tid >> 6) << 9);   // wid*512 elems (uniform)
  #pragma unroll
  for (int r = 0; r < 4; ++r)
    gload16(src + (long long)r * 32 * DD, dstbase + r * 2048);
}

// ---- GEMM core: acc += A[128 rows @brow] @ B[128 rows @bcol]^T over K=512 ---
// Double-buffered LDS, depth-1 prefetch (T3-minimum): STAGE(t+1) issued before
// compute(t); the __syncthreads() at step end forces the vmcnt drain of the
// prefetch, whose latency hid under this step's ds_read+MFMA.

__device__ __forceinline__ void gemm_core64(
    const unsigned short* __restrict__ A, const unsigned short* __restrict__ B,
    unsigned short* As, unsigned short* Bs,   // each [2][128*64] elements
    long long brow, long long bcol, int wr, int wc, int lane, int tid,
    f32x4 acc[4][4]) {
  const int rA = wr * 64 + (lane & 15);
  const int rB = wc * 64 + (lane & 15);
  const int c16b = lane >> 4;            // 0..3

  stage_tile(A, brow, 0, As, tid);
  stage_tile(B, bcol, 0, Bs, tid);
  __syncthreads();   // compiler emits vmcnt(0) drain here

  for (int kt = 0; kt < NT; ++kt) {
    const int cur = kt & 1;
    if (kt + 1 < NT) {
      stage_tile(A, brow, (kt + 1) * BK, As + (cur ^ 1) * 8192, tid);
      stage_tile(B, bcol, (kt + 1) * BK, Bs + (cur ^ 1) * 8192, tid);
    }
    const unsigned short* as = As + cur * 8192;
    const unsigned short* bs = Bs + cur * 8192;
    #pragma unroll
    for (int kk = 0; kk < 2; ++kk) {
      bf16x8 a[4], b[4];
      #pragma unroll
      for (int m = 0; m < 4; ++m) {
        const int row = rA + m * 16;
        const int c16 = (c16b + kk * 4) ^ (row & 7);
        a[m] = *reinterpret_cast<const bf16x8*>(as + row * 64 + c16 * 8);
      }
      #pragma unroll
      for (int n = 0; n < 4; ++n) {
        const int row = rB + n * 16;
        const int c16 = (c16b + kk * 4) ^ (row & 7);
        b[n] = *reinterpret_cast<const bf16x8*>(bs + row * 64 + c16 * 8);
      }
      #pragma unroll
      for (int m = 0; m < 4; ++m)
        #pragma unroll
        for (int n = 0; n < 4; ++n)
          acc[m][n] = __builtin_amdgcn_mfma_f32_16x16x32_bf16(a[m], b[n], acc[m][n], 0, 0, 0);
    }
    __syncthreads();   // drains prefetch (vmcnt(0)) + protects buffer swap
  }
}

// ---- FF GEMM: C = relu(A@W^T + bias)  [DUAL: + A2@W2^T + bias2] ------------
// Combined grid: tiles [0, nwgL) = l-problem (gridX=4), rest = g-problem.

template <int DUAL>
__global__ __launch_bounds__(256, 2) void gemm_ff_kernel(
    const unsigned short* __restrict__ Al, const unsigned short* __restrict__ Wl,
    const float* __restrict__ biasl, unsigned short* __restrict__ Cl,
    const unsigned short* __restrict__ A2l, const unsigned short* __restrict__ W2l,
    const float* __restrict__ bias2l, int nwgL,
    const unsigned short* __restrict__ Ag, const unsigned short* __restrict__ Wg,
    const float* __restrict__ biasg, unsigned short* __restrict__ Cg,
    const unsigned short* __restrict__ A2g, const unsigned short* __restrict__ W2g,
    const float* __restrict__ bias2g) {
  __shared__ unsigned short As[2 * 8192];
  __shared__ unsigned short Bs[2 * 8192];
  const int tid = threadIdx.x;
  const int lane = tid & 63, wid = tid >> 6;
  const int wr = wid >> 1, wc = wid & 1;

  int tile = xcd_remap(blockIdx.x, gridDim.x);
  const unsigned short *A, *W, *A2, *W2;
  const float *bias, *bias2;
  unsigned short* C;
  if (tile < nwgL) {
    A = Al; W = Wl; bias = biasl; C = Cl; A2 = A2l; W2 = W2l; bias2 = bias2l;
  } else {
    tile -= nwgL;
    A = Ag; W = Wg; bias = biasg; C = Cg; A2 = A2g; W2 = W2g; bias2 = bias2g;
  }
  const long long brow = (long long)(tile >> 2) * 128;
  const long long bcol = (long long)(tile & 3) * 128;

  f32x4 zero = {0.f, 0.f, 0.f, 0.f};
  f32x4 acc[4][4];
  #pragma unroll
  for (int m = 0; m < 4; ++m)
    #pragma unroll
    for (int n = 0; n < 4; ++n) acc[m][n] = zero;

  gemm_core64(A, W, As, Bs, brow, bcol, wr, wc, lane, tid, acc);

  float bv[4];
  #pragma unroll
  for (int n = 0; n < 4; ++n) bv[n] = bias[bcol + wc * 64 + n * 16 + (lane & 15)];

  if constexpr (DUAL) {
    float r[4][4][4];
    #pragma unroll
    for (int m = 0; m < 4; ++m)
      #pragma unroll
      for (int n = 0; n < 4; ++n)
        #pragma unroll
        for (int j = 0; j < 4; ++j)
          r[m][n][j] = fmaxf(acc[m][n][j] + bv[n], 0.f);
    #pragma unroll
    for (int m = 0; m < 4; ++m)
      #pragma unroll
      for (int n = 0; n < 4; ++n) acc[m][n] = zero;

    gemm_core64(A2, W2, As, Bs, brow, bcol, wr, wc, lane, tid, acc);

    float b2[4];
    #pragma unroll
    for (int n = 0; n < 4; ++n) b2[n] = bias2[bcol + wc * 64 + n * 16 + (lane & 15)];

    #pragma unroll
    for (int m = 0; m < 4; ++m) {
      const long long row = brow + wr * 64 + m * 16 + (lane >> 4) * 4;
      #pragma unroll
      for (int j = 0; j < 4; ++j)
        #pragma unroll
        for (int n = 0; n < 4; ++n) {
          const long long col = bcol + wc * 64 + n * 16 + (lane & 15);
          float v = r[m][n][j] + acc[m][n][j] + b2[n];
          C[(row + j) * DD + col] = f2bf(v);
        }
    }
  } else {
    #pragma unroll
    for (int m = 0; m < 4; ++m) {
      const long long row = brow + wr * 64 + m * 16 + (lane >> 4) * 4;
      #pragma unroll
      for (int j = 0; j < 4; ++j)
        #pragma unroll
        for (int n = 0; n < 4; ++n) {
          const long long col = bcol + wc * 64 + n * 16 + (lane & 15);
          float v = fmaxf(acc[m][n][j] + bv[n], 0.f);
          C[(row + j) * DD + col] = f2bf(v);
        }
    }
  }
}

// ---- res GEMM + fused JSD reduction ----------------------------------------
// accum[0] = sum_diag (LN2 - softplus(-v))
// accum[1] = sum_all  (softplus(-v) + v)
// accum[2] = sum_diag (softplus(-v) + v)

__global__ __launch_bounds__(256, 2) void gemm_jsd_kernel(
    const unsigned short* __restrict__ A, const unsigned short* __restrict__ B,
    const int* __restrict__ batch, double* __restrict__ accum) {
  __shared__ unsigned short As[2 * 8192];
  __shared__ unsigned short Bs[2 * 8192];
  __shared__ int sbatch[128];
  __shared__ float sred[12];
  const int tid = threadIdx.x;
  const int lane = tid & 63, wid = tid >> 6;
  const int wr = wid >> 1, wc = wid & 1;

  const int tile = xcd_remap(blockIdx.x, gridDim.x);
  const long long brow = (long long)(tile >> 3) * 128;
  const long long bcol = (long long)(tile & 7) * 128;

  if (tid < 128) {
    long long gr = brow + tid;
    sbatch[tid] = (gr < N_NODE) ? batch[gr] : -1;  // -1: never matches a col
  }

  f32x4 zero = {0.f, 0.f, 0.f, 0.f};
  f32x4 acc[4][4];
  #pragma unroll
  for (int m = 0; m < 4; ++m)
    #pragma unroll
    for (int n = 0; n < 4; ++n) acc[m][n] = zero;

  gemm_core64(A, B, As, Bs, brow, bcol, wr, wc, lane, tid, acc);

  const float LN2 = 0.69314718055994530942f;
  float sAll = 0.f, sPos = 0.f, sDiag = 0.f;
  #pragma unroll
  for (int m = 0; m < 4; ++m) {
    #pragma unroll
    for (int j = 0; j < 4; ++j) {
      const int lr = wr * 64 + m * 16 + (lane >> 4) * 4 + j;
      const int bg = sbatch[lr];
      #pragma unroll
      for (int n = 0; n < 4; ++n) {
        const int col = (int)bcol + wc * 64 + n * 16 + (lane & 15);
        float v = acc[m][n][j];
        float t = __expf(-fabsf(v));
        float spn = fmaxf(-v, 0.f) + __logf(1.0f + t);   // softplus(-v)
        sAll += spn + v;
        if (col == bg) {
          sPos += LN2 - spn;
          sDiag += spn + v;
        }
      }
    }
  }
  #pragma unroll
  for (int off = 32; off > 0; off >>= 1) {
    sAll  += __shfl_down(sAll, off);
    sPos  += __shfl_down(sPos, off);
    sDiag += __shfl_down(sDiag, off);
  }
  if (lane == 0) { sred[wid] = sPos; sred[4 + wid] = sAll; sred[8 + wid] = sDiag; }
  __syncthreads();
  if (tid == 0) {
    float p = sred[0] + sred[1] + sred[2] + sred[3];
    float a = sred[4] + sred[5] + sred[6] + sred[7];
    float d = sred[8] + sred[9] + sred[10] + sred[11];
    atomicAdd(accum,     (double)p);
    atomicAdd(accum + 1, (double)a);
    atomicAdd(accum + 2, (double)d);
  }
}

__global__ void finalize_kernel(const double* __restrict__ accum,
                                float* __restrict__ out) {
  if (threadIdx.x == 0 && blockIdx.x == 0) {
    const double LN2 = 0.6931471805599453094172321;
    double posSum = accum[0];
    double negSum = (accum[1] - accum[2])
                  - ((double)N_PAD * N_GRAPH - (double)N_NODE) * LN2;
    double Epos = posSum / (double)N_NODE;
    double Eneg = negSum / ((double)N_NODE * (double)(N_GRAPH - 1));
    out[0] = (float)(Eneg - Epos);
  }
}

// ---- launch -----------------------------------------------------------------

extern "C" void kernel_launch(void* const* d_in, const int* in_sizes, int n_in,
                              void* d_out, int out_size, void* d_ws, size_t ws_size,
                              hipStream_t stream) {
  const float* node  = (const float*)d_in[0];
  const float* graph = (const float*)d_in[1];
  const int*   batch = (const int*)d_in[2];
  const float* lw0 = (const float*)d_in[3];
  const float* lb0 = (const float*)d_in[4];
  const float* lw1 = (const float*)d_in[5];
  const float* lb1 = (const float*)d_in[6];
  const float* lw2 = (const float*)d_in[7];
  const float* lb2 = (const float*)d_in[8];
  const float* lws = (const float*)d_in[9];
  const float* lbs = (const float*)d_in[10];
  const float* gw0 = (const float*)d_in[11];
  const float* gb0 = (const float*)d_in[12];
  const float* gw1 = (const float*)d_in[13];
  const float* gb1 = (const float*)d_in[14];
  const float* gw2 = (const float*)d_in[15];
  const float* gb2 = (const float*)d_in[16];
  const float* gws = (const float*)d_in[17];
  const float* gbs = (const float*)d_in[18];

  // workspace layout (bytes, 256-aligned)
  char* ws = (char*)d_ws;
  double*         accum = (double*)ws;                          // 24 B
  unsigned short* WB  = (unsigned short*)(ws + 256);            // 8 x 512x512 bf16
  unsigned short* XB  = (unsigned short*)(ws + 4194560LL);      // [N_PAD,512] bf16
  unsigned short* H1  = (unsigned short*)(ws + 55443712LL);
  unsigned short* H2  = (unsigned short*)(ws + 106692864LL);
  unsigned short* GXB = (unsigned short*)(ws + 157942016LL);
  unsigned short* GH1 = (unsigned short*)(ws + 158990592LL);
  unsigned short* GH2 = (unsigned short*)(ws + 160039168LL);
  if (ws_size < 161087744ULL) return;  // workspace too small: fail loudly

  hipMemsetAsync(accum, 0, 32, stream);

  WPtrs wp;
  wp.p[0] = lw0; wp.p[1] = lw1; wp.p[2] = lw2; wp.p[3] = lws;
  wp.p[4] = gw0; wp.p[5] = gw1; wp.p[6] = gw2; wp.p[7] = gws;
  cast_w_kernel<<<1024, 256, 0, stream>>>(wp, WB);
  cast_pad_kernel<<<12512, 256, 0, stream>>>(node, XB, N_NODE, N_PAD);
  cast_pad_kernel<<<256, 256, 0, stream>>>(graph, GXB, N_GRAPH, N_GRAPH);

  dim3 blk(256);
  const int nwgL = 4 * 391;           // l-problem tiles (gridX=4)
  const int nwgG = 4 * 8;             // g-problem tiles
  dim3 gff(nwgL + nwgG);
  dim3 gr(8 * 391);                   // res: gridX=8, 391 row tiles

  gemm_ff_kernel<0><<<gff, blk, 0, stream>>>(
      XB, WB + 0 * 262144, lb0, H1, nullptr, nullptr, nullptr, nwgL,
      GXB, WB + 4 * 262144, gb0, GH1, nullptr, nullptr, nullptr);
  gemm_ff_kernel<0><<<gff, blk, 0, stream>>>(
      H1, WB + 1 * 262144, lb1, H2, nullptr, nullptr, nullptr, nwgL,
      GH1, WB + 5 * 262144, gb1, GH2, nullptr, nullptr, nullptr);
  gemm_ff_kernel<1><<<gff, blk, 0, stream>>>(
      H2, WB + 2 * 262144, lb2, H1, XB, WB + 3 * 262144, lbs, nwgL,
      GH2, WB + 6 * 262144, gb2, GH1, GXB, WB + 7 * 262144, gbs);

  gemm_jsd_kernel<<<gr, blk, 0, stream>>>(H1, GH1, batch, accum);
  finalize_kernel<<<1, 64, 0, stream>>>(accum, (float*)d_out);
}